// Round 14
// baseline (68.531 us; speedup 1.0000x reference)
//
#include <hip/hip_runtime.h>
#include <cstddef>

#define BB 4
#define NN 256
#define HH 256
#define BN_EPS 1e-5f
#define ETA_EPS 1e-20f

typedef float f4 __attribute__((ext_vector_type(4)));

__device__ __forceinline__ float fast_sigmoid(float x) {
    float ex = __expf(-x);
    return __builtin_amdgcn_rcpf(1.f + ex);
}

// ---------------------------------------------------------------------------
// Kernel 1: projections DIRECTLY from W (nn.Linear y = x @ W^T) with an
// in-kernel double-buffered LDS transpose of W tiles. Replaces the separate
// transpose kernel (one fewer launch + gap).
// Grid 513 x 256 thr: block 512 zeroes Ssum/Qsum; blocks 0..511:
//   wg = blk>>2 (8-row group), which = (blk>>1)&1, oh = blk&1 (output half).
// Per block: 8 tiles of 32 h. Stage W[o][htile] (128 o x 32 h = 16 KB)
// coalesced, LDS-transposed; each thread owns (row rg, out-quad oq) and
// accumulates the FULL dot product -> no cross-wave reduction at the end.
// ---------------------------------------------------------------------------
__global__ __launch_bounds__(256) void proj_kernel(
    const float* __restrict__ nodes, const float* __restrict__ W1,
    const float* __restrict__ W2, float* __restrict__ xleft,
    float* __restrict__ xw2, float* __restrict__ Ssum,
    float* __restrict__ Qsum)
{
    if (blockIdx.x == 512) {           // stats-accumulator zeroing
        Ssum[threadIdx.x] = 0.f;
        Qsum[threadIdx.x] = 0.f;
        return;
    }
    const int wg    = blockIdx.x >> 2;       // 8-row group, 0..127
    const int which = (blockIdx.x >> 1) & 1; // 0 -> W1/xleft, 1 -> W2/xw2
    const int oh    = blockIdx.x & 1;        // output half (128 outputs)
    const float* __restrict__ W = which ? W2 : W1;
    float* __restrict__ dst     = which ? xw2 : xleft;
    const int t = threadIdx.x;

    __shared__ float xs[8][HH];        // 8 KB: the 8 node rows
    __shared__ float wt[2][32][128];   // 32 KB: double-buffered W^T tile

    {
        f4* xs4 = reinterpret_cast<f4*>(xs);
        const f4* nodes4 = reinterpret_cast<const f4*>(nodes) + wg * 512;
        xs4[t]       = nodes4[t];
        xs4[t + 256] = nodes4[t + 256];
    }

    const int rg = t >> 5;             // node row 0..7
    const int oq = t & 31;             // output f4 quad within half
    const int lr = t >> 3;             // staging: base o row 0..31
    const int lc = t & 7;              // staging: f4 col within 32-h tile
    const f4* __restrict__ W4 = reinterpret_cast<const f4*>(W);

    // stage tile h0 into wt[buf]: W[oh*128+o][h0+4*lc .. +3] -> wt[4lc+k][o]
#define STAGE(buf, h0)                                                        \
    {                                                                         \
        _Pragma("unroll")                                                     \
        for (int m = 0; m < 4; ++m) {                                         \
            int o = lr + m * 32;                                              \
            f4 w = W4[(size_t)(oh * 128 + o) * 64 + ((h0) >> 2) + lc];        \
            _Pragma("unroll")                                                 \
            for (int k = 0; k < 4; ++k) wt[buf][lc * 4 + k][o] = w[k];        \
        }                                                                     \
    }

    STAGE(0, 0);
    __syncthreads();

    f4 acc = (f4){0.f, 0.f, 0.f, 0.f};
#pragma unroll
    for (int tile = 0; tile < 8; ++tile) {
        const int buf = tile & 1;
        if (tile < 7) STAGE(buf ^ 1, (tile + 1) * 32);
        const f4* wrow = reinterpret_cast<const f4*>(wt[buf]);
        const float* xr = &xs[rg][tile * 32];
#pragma unroll
        for (int hh = 0; hh < 32; ++hh)
            acc += xr[hh] * wrow[hh * 32 + oq];   // xs broadcast, wt 2-way
        __syncthreads();
    }
#undef STAGE

    reinterpret_cast<f4*>(dst)[(wg * 8 + rg) * 64 + oh * 32 + oq] = acc;
}

// ---------------------------------------------------------------------------
// Kernel 2: edge aggregation (R11/R13-proven) + fused per-channel BN stats
// partials via atomicAdd. Byte-identical to R13.
// ---------------------------------------------------------------------------
__global__ __launch_bounds__(1024) void edge_kernel(
    const float* __restrict__ edges, const float* __restrict__ xw2,
    const float* __restrict__ xleft, float* __restrict__ equ,
    float* __restrict__ Ssum, float* __restrict__ Qsum)
{
    const int blk = blockIdx.x;
    const int ig  = blk >> 2;          // i-group of 8 rows: 0..127
    const int hs4 = (blk & 3) * 16;    // first f4 quad of 64-ch slice
    const int bi0 = ig * 8;
    const int b   = bi0 >> 8;
    const int t   = threadIdx.x;

    __shared__ f4 xw_s[NN][16];        // 64 KB; overlaid by reduction later

    const f4* __restrict__ xw4 =
        reinterpret_cast<const f4*>(xw2) + (size_t)b * NN * 64;
#pragma unroll
    for (int m = 0; m < 4; ++m) {
        int idx = m * 1024 + t;
        int j = idx >> 4, q = idx & 15;
        xw_s[j][q] = xw4[j * 64 + hs4 + q];
    }
    __syncthreads();

    const int q  = t & 15;             // channel quad within slice
    const int il = (t >> 4) & 7;       // i within tile
    const int jg = t >> 7;             // 0..7, j stride group

    const f4* __restrict__ erow =
        reinterpret_cast<const f4*>(edges) +
        (size_t)(bi0 + il) * (NN * 64) + hs4 + q;

    float s0[4] = {0.f, 0.f, 0.f, 0.f};
    float s1[4] = {0.f, 0.f, 0.f, 0.f};

#pragma unroll 2
    for (int j = jg; j < NN; j += 8) {
        f4 e  = erow[j * 64];          // plain load
        f4 xw = xw_s[j][q];
#pragma unroll
        for (int k = 0; k < 4; ++k) {
            float sg = fast_sigmoid(e[k]);
            s0[k] += sg;
            s1[k] += sg * xw[k];
        }
    }
    __syncthreads();                   // xw_s dead; reuse for reduction

    float* red = reinterpret_cast<float*>(xw_s);
    {
        float* r0 = red + ((jg * 8 + il) * 16 + q) * 4;
        float* r1 = r0 + 4096;
#pragma unroll
        for (int k = 0; k < 4; ++k) { r0[k] = s0[k]; r1[k] = s1[k]; }
    }
    __syncthreads();

    float* st = red + 8192;            // [8 rows][64 ch][2]

    if (t < 512) {
        const int il2 = t >> 6;        // 0..7
        const int ch  = t & 63;        // channel within slice
        float S0 = 0.f, S1 = 0.f;
#pragma unroll
        for (int g = 0; g < 8; ++g) {
            S0 += red[(g * 8 + il2) * 64 + ch];
            S1 += red[(g * 8 + il2) * 64 + ch + 4096];
        }
        const size_t off = (size_t)(bi0 + il2) * HH + hs4 * 4 + ch;
        float ov = xleft[off] + S1 / (S0 + ETA_EPS);
        equ[off] = ov;
        st[(il2 * 64 + ch) * 2]     = ov;
        st[(il2 * 64 + ch) * 2 + 1] = ov * ov;
    }
    __syncthreads();

    if (t < 64) {
        float S = 0.f, Q = 0.f;
#pragma unroll
        for (int g = 0; g < 8; ++g) {
            S += st[(g * 64 + t) * 2];
            Q += st[(g * 64 + t) * 2 + 1];
        }
        atomicAdd(&Ssum[hs4 * 4 + t], S);
        atomicAdd(&Qsum[hs4 * 4 + t], Q);
    }
}

// ---------------------------------------------------------------------------
// Kernel 3: normalize with inline scale/shift from the atomic accumulators.
// Byte-identical to R13.
// ---------------------------------------------------------------------------
__global__ __launch_bounds__(256) void norm_kernel(
    const float* __restrict__ equ, const float* __restrict__ Ssum,
    const float* __restrict__ Qsum, const float* __restrict__ gamma,
    const float* __restrict__ beta, float* __restrict__ out)
{
    const int idx = blockIdx.x * 256 + threadIdx.x;   // f4 index
    const int c4  = idx & 63;
    f4 e = reinterpret_cast<const f4*>(equ)[idx];
    f4 S = reinterpret_cast<const f4*>(Ssum)[c4];
    f4 Q = reinterpret_cast<const f4*>(Qsum)[c4];
    f4 g = reinterpret_cast<const f4*>(gamma)[c4];
    f4 b = reinterpret_cast<const f4*>(beta)[c4];

    const float inv_n = 1.f / (float)(BB * NN);
    f4 o;
#pragma unroll
    for (int k = 0; k < 4; ++k) {
        float mean = S[k] * inv_n;
        float var  = Q[k] * inv_n - mean * mean;
        float rstd = rsqrtf(var + BN_EPS);
        o[k] = (e[k] - mean) * rstd * g[k] + b[k];
    }
    reinterpret_cast<f4*>(out)[idx] = o;
}

// ---------------------------------------------------------------------------
extern "C" void kernel_launch(void* const* d_in, const int* in_sizes, int n_in,
                              void* d_out, int out_size, void* d_ws, size_t ws_size,
                              hipStream_t stream) {
    (void)in_sizes; (void)n_in; (void)out_size; (void)ws_size;

    const float* nodes = (const float*)d_in[0];
    const float* edges = (const float*)d_in[1];
    const float* W1    = (const float*)d_in[2];
    const float* W2    = (const float*)d_in[3];
    const float* gamma = (const float*)d_in[4];
    const float* beta  = (const float*)d_in[5];
    float* out = (float*)d_out;

    const int nBN_H = BB * NN * HH;  // 262144
    float* ws    = (float*)d_ws;
    float* xleft = ws;
    float* xw2   = ws + nBN_H;
    float* equ   = ws + 2 * nBN_H;
    float* Ssum  = ws + 3 * nBN_H;
    float* Qsum  = Ssum + HH;

    proj_kernel<<<513, 256, 0, stream>>>(nodes, W1, W2, xleft, xw2, Ssum, Qsum);
    edge_kernel<<<512, 1024, 0, stream>>>(edges, xw2, xleft, equ, Ssum, Qsum);
    norm_kernel<<<256, 256, 0, stream>>>(equ, Ssum, Qsum, gamma, beta, out);
}

// Round 15
// 61.539 us; speedup vs baseline: 1.1136x; 1.1136x over previous
//
#include <hip/hip_runtime.h>
#include <cstddef>

#define BB 4
#define NN 256
#define HH 256
#define BN_EPS 1e-5f
#define ETA_EPS 1e-20f

typedef float f4 __attribute__((ext_vector_type(4)));

__device__ __forceinline__ float fast_sigmoid(float x) {
    float ex = __expf(-x);
    return __builtin_amdgcn_rcpf(1.f + ex);
}

// ---------------------------------------------------------------------------
// Kernel 0: transpose W1,W2 -> WT1,WT2; block 32 zeros the stats accumulators
// (R13-proven).
// ---------------------------------------------------------------------------
__global__ __launch_bounds__(256) void transpose_kernel(
    const float* __restrict__ W1, const float* __restrict__ W2,
    float* __restrict__ WT1, float* __restrict__ WT2,
    float* __restrict__ Ssum, float* __restrict__ Qsum)
{
    if (blockIdx.x == 32) {
        Ssum[threadIdx.x] = 0.f;
        Qsum[threadIdx.x] = 0.f;
        return;
    }
    const int which = blockIdx.x >> 4;
    const int tile  = blockIdx.x & 15;
    const int tr = (tile >> 2) << 6, tc = (tile & 3) << 6;
    const float* __restrict__ W  = which ? W2 : W1;
    float* __restrict__ WT       = which ? WT2 : WT1;

    __shared__ float tl[64][65];
    const int c = threadIdx.x & 63, p0 = threadIdx.x >> 6;
#pragma unroll
    for (int p = 0; p < 16; ++p) {
        int r = p * 4 + p0;
        tl[c][r] = W[(tr + r) * HH + tc + c];
    }
    __syncthreads();
#pragma unroll
    for (int p = 0; p < 16; ++p) {
        int cc = p * 4 + p0;
        WT[(tc + cc) * HH + tr + c] = tl[cc][c];
    }
}

// ---------------------------------------------------------------------------
// Kernel 1: projections via WT (R13-proven). 512 blocks x 256 thr:
// blk = wg*4 + which*2 + oh. Block = 8 rows x 128 outputs -> 2 blocks/CU.
// ---------------------------------------------------------------------------
__global__ __launch_bounds__(256) void proj_kernel(
    const float* __restrict__ nodes, const float* __restrict__ WT1,
    const float* __restrict__ WT2, float* __restrict__ xleft,
    float* __restrict__ xw2)
{
    const int wg    = blockIdx.x >> 2;       // 8-row group, 0..127
    const int which = (blockIdx.x >> 1) & 1; // 0 -> W1/xleft, 1 -> W2/xw2
    const int oh    = blockIdx.x & 1;        // output half (32 f4 quads)
    const float* __restrict__ WT = which ? WT2 : WT1;
    float* __restrict__ dst      = which ? xw2 : xleft;
    const int t = threadIdx.x;

    __shared__ float xs[8][HH];              // 8 KB
    {
        f4* xs4 = reinterpret_cast<f4*>(xs);
        const f4* nodes4 = reinterpret_cast<const f4*>(nodes) + wg * 512;
        xs4[t]       = nodes4[t];
        xs4[t + 256] = nodes4[t + 256];
    }
    __syncthreads();

    const int oq = t & 31;                   // f4 quad within this half
    const int hg = t >> 5;                   // h-group 0..7 (32 h each)
    const f4* __restrict__ WT4 = reinterpret_cast<const f4*>(WT);

    f4 acc[8];
#pragma unroll
    for (int r = 0; r < 8; ++r) acc[r] = (f4){0.f, 0.f, 0.f, 0.f};

    for (int hh = 0; hh < 32; ++hh) {
        const int h = hg * 32 + hh;
        f4 wv = WT4[h * 64 + oh * 32 + oq];  // 512 B contiguous per hg-half
#pragma unroll
        for (int r = 0; r < 8; ++r)
            acc[r] += xs[r][h] * wv;         // LDS broadcast
    }

    __shared__ f4 ps[8][8][32];              // 32 KB  [hg][r][oq]
#pragma unroll
    for (int r = 0; r < 8; ++r) ps[hg][r][oq] = acc[r];
    __syncthreads();

    {
        const int r = t >> 5, o = t & 31;    // 256 threads = 8 r x 32 oq
        f4 v = (f4){0.f, 0.f, 0.f, 0.f};
#pragma unroll
        for (int g = 0; g < 8; ++g) v += ps[g][r][o];
        reinterpret_cast<f4*>(dst)[(wg * 8 + r) * 64 + oh * 32 + o] = v;
    }
}

// ---------------------------------------------------------------------------
// Kernel 2: edge aggregation + fused BN stats (R13 structure). ONE change:
// j-loop unroll 2 -> 4 (1 KB e-loads in flight per wave, 32 KB/CU — safely
// above the ~8.3 B/cyc x ~900 cyc Little's-law requirement; R13's 16 KB/CU
// was marginal).
// ---------------------------------------------------------------------------
__global__ __launch_bounds__(1024) void edge_kernel(
    const float* __restrict__ edges, const float* __restrict__ xw2,
    const float* __restrict__ xleft, float* __restrict__ equ,
    float* __restrict__ Ssum, float* __restrict__ Qsum)
{
    const int blk = blockIdx.x;
    const int ig  = blk >> 2;          // i-group of 8 rows: 0..127
    const int hs4 = (blk & 3) * 16;    // first f4 quad of 64-ch slice
    const int bi0 = ig * 8;
    const int b   = bi0 >> 8;
    const int t   = threadIdx.x;

    __shared__ f4 xw_s[NN][16];        // 64 KB; overlaid by reduction later

    const f4* __restrict__ xw4 =
        reinterpret_cast<const f4*>(xw2) + (size_t)b * NN * 64;
#pragma unroll
    for (int m = 0; m < 4; ++m) {
        int idx = m * 1024 + t;
        int j = idx >> 4, q = idx & 15;
        xw_s[j][q] = xw4[j * 64 + hs4 + q];
    }
    __syncthreads();

    const int q  = t & 15;             // channel quad within slice
    const int il = (t >> 4) & 7;       // i within tile
    const int jg = t >> 7;             // 0..7, j stride group

    const f4* __restrict__ erow =
        reinterpret_cast<const f4*>(edges) +
        (size_t)(bi0 + il) * (NN * 64) + hs4 + q;

    float s0[4] = {0.f, 0.f, 0.f, 0.f};
    float s1[4] = {0.f, 0.f, 0.f, 0.f};

#pragma unroll 4
    for (int j = jg; j < NN; j += 8) {
        f4 e  = erow[j * 64];          // plain load
        f4 xw = xw_s[j][q];
#pragma unroll
        for (int k = 0; k < 4; ++k) {
            float sg = fast_sigmoid(e[k]);
            s0[k] += sg;
            s1[k] += sg * xw[k];
        }
    }
    __syncthreads();                   // xw_s dead; reuse for reduction

    float* red = reinterpret_cast<float*>(xw_s);
    {
        float* r0 = red + ((jg * 8 + il) * 16 + q) * 4;
        float* r1 = r0 + 4096;
#pragma unroll
        for (int k = 0; k < 4; ++k) { r0[k] = s0[k]; r1[k] = s1[k]; }
    }
    __syncthreads();

    float* st = red + 8192;            // [8 rows][64 ch][2]

    if (t < 512) {
        const int il2 = t >> 6;        // 0..7
        const int ch  = t & 63;        // channel within slice
        float S0 = 0.f, S1 = 0.f;
#pragma unroll
        for (int g = 0; g < 8; ++g) {
            S0 += red[(g * 8 + il2) * 64 + ch];
            S1 += red[(g * 8 + il2) * 64 + ch + 4096];
        }
        const size_t off = (size_t)(bi0 + il2) * HH + hs4 * 4 + ch;
        float ov = xleft[off] + S1 / (S0 + ETA_EPS);
        equ[off] = ov;
        st[(il2 * 64 + ch) * 2]     = ov;
        st[(il2 * 64 + ch) * 2 + 1] = ov * ov;
    }
    __syncthreads();

    if (t < 64) {
        float S = 0.f, Q = 0.f;
#pragma unroll
        for (int g = 0; g < 8; ++g) {
            S += st[(g * 64 + t) * 2];
            Q += st[(g * 64 + t) * 2 + 1];
        }
        atomicAdd(&Ssum[hs4 * 4 + t], S);
        atomicAdd(&Qsum[hs4 * 4 + t], Q);
    }
}

// ---------------------------------------------------------------------------
// Kernel 3: normalize with inline scale/shift (R13-proven).
// ---------------------------------------------------------------------------
__global__ __launch_bounds__(256) void norm_kernel(
    const float* __restrict__ equ, const float* __restrict__ Ssum,
    const float* __restrict__ Qsum, const float* __restrict__ gamma,
    const float* __restrict__ beta, float* __restrict__ out)
{
    const int idx = blockIdx.x * 256 + threadIdx.x;   // f4 index
    const int c4  = idx & 63;
    f4 e = reinterpret_cast<const f4*>(equ)[idx];
    f4 S = reinterpret_cast<const f4*>(Ssum)[c4];
    f4 Q = reinterpret_cast<const f4*>(Qsum)[c4];
    f4 g = reinterpret_cast<const f4*>(gamma)[c4];
    f4 b = reinterpret_cast<const f4*>(beta)[c4];

    const float inv_n = 1.f / (float)(BB * NN);
    f4 o;
#pragma unroll
    for (int k = 0; k < 4; ++k) {
        float mean = S[k] * inv_n;
        float var  = Q[k] * inv_n - mean * mean;
        float rstd = rsqrtf(var + BN_EPS);
        o[k] = (e[k] - mean) * rstd * g[k] + b[k];
    }
    reinterpret_cast<f4*>(out)[idx] = o;
}

// ---------------------------------------------------------------------------
extern "C" void kernel_launch(void* const* d_in, const int* in_sizes, int n_in,
                              void* d_out, int out_size, void* d_ws, size_t ws_size,
                              hipStream_t stream) {
    (void)in_sizes; (void)n_in; (void)out_size; (void)ws_size;

    const float* nodes = (const float*)d_in[0];
    const float* edges = (const float*)d_in[1];
    const float* W1    = (const float*)d_in[2];
    const float* W2    = (const float*)d_in[3];
    const float* gamma = (const float*)d_in[4];
    const float* beta  = (const float*)d_in[5];
    float* out = (float*)d_out;

    const int nBN_H = BB * NN * HH;  // 262144
    float* ws    = (float*)d_ws;
    float* xleft = ws;
    float* xw2   = ws + nBN_H;
    float* equ   = ws + 2 * nBN_H;
    float* WT1   = ws + 3 * nBN_H;
    float* WT2   = WT1 + HH * HH;
    float* Ssum  = WT2 + HH * HH;
    float* Qsum  = Ssum + HH;

    transpose_kernel<<<33, 256, 0, stream>>>(W1, W2, WT1, WT2, Ssum, Qsum);
    proj_kernel<<<512, 256, 0, stream>>>(nodes, WT1, WT2, xleft, xw2);
    edge_kernel<<<512, 1024, 0, stream>>>(edges, xw2, xleft, equ, Ssum, Qsum);
    norm_kernel<<<256, 256, 0, stream>>>(equ, Ssum, Qsum, gamma, beta, out);
}